// Round 2
// baseline (3997.571 us; speedup 1.0000x reference)
//
#include <hip/hip_runtime.h>
#include <cstddef>

// ---------------------------------------------------------------------------
// MT_RNN: y_t = MLP(h_t);  h_{t+1} = (1-a) h_t + a tanh(zx_t + h_t Whh^T + bhh)
// Single 256 MB scratch buffer (in-place GEMMs: each block reads only its own
// 64 rows, all reads precede its stores, rows are block-exclusive):
//   1) buf = tanh(x Wx0^T + bx0)                [262144,64] -> [.,256]
//   2) buf = tanh(buf Wx1^T + bx1)              in-place
//   3) buf = buf Wih^T + bih        (= zx)      in-place
//   4) serial: evolve h over T, store h_t over consumed zx[t]   in-place
//   5) buf = tanh(buf Wh0^T + bh0)              in-place
//   6) buf = tanh(buf Wh1^T + bh1)              in-place
//   7) out = buf Wg^T + bg                      [262144,64]
// ws requirement: 262144*256*4 B = 256 MB exactly.
// ---------------------------------------------------------------------------

typedef __bf16 bf16x8 __attribute__((ext_vector_type(8)));
typedef float  f32x4  __attribute__((ext_vector_type(4)));

#define T_LEN 1024
#define B_SZ  256
#define H_DIM 256
#define M_ROWS (T_LEN * B_SZ)  // 262144

__device__ __forceinline__ float fast_tanh(float x) {
  // tanh(x) = 1 - 2/(e^{2x}+1); handles +-inf saturation correctly.
  float e = __expf(2.0f * x);
  return 1.0f - 2.0f / (e + 1.0f);
}

// alphas: sorted assignment of [0.001,0.01,0.1] over 256 units:
// 86 x 0.001, 85 x 0.01, 85 x 0.1
__device__ __forceinline__ float alpha_of(int j) {
  return (j < 86) ? 0.001f : ((j < 171) ? 0.01f : 0.1f);
}

// ---------------------------------------------------------------------------
// Generic fp32 GEMM: C[M,BN] = act(A[M,K] @ W[BN,K]^T + bias), tile 64 x BN.
// A and C may be the SAME buffer (in-place): block bm reads only rows
// [64bm,64bm+64) of A (all during the k-loop) and writes only those rows of C
// (after the k-loop). No __restrict__ on A/C because they may alias.
// ---------------------------------------------------------------------------
template <int NG, bool TANH>
__global__ __launch_bounds__(256)
void gemm_bias_act(const float* A, const float* __restrict__ W,
                   const float* __restrict__ bias, float* C, int K) {
  constexpr int BN = NG * 64;
  __shared__ __attribute__((aligned(16))) float As[16][68];
  __shared__ __attribute__((aligned(16))) float Ws[16][BN + 4];

  const int tid = threadIdx.x;
  const int bm  = blockIdx.x;
  const int tx  = tid & 15;
  const int ty  = tid >> 4;

  float acc[4][NG * 4];
#pragma unroll
  for (int i = 0; i < 4; i++)
#pragma unroll
    for (int j = 0; j < NG * 4; j++) acc[i][j] = 0.0f;

  const int lm = tid >> 2;  // A staging: row within tile
  const int lq = tid & 3;   // A staging: k quad
  const float* Abase = A + (size_t)(bm * 64) * K;

  for (int k0 = 0; k0 < K; k0 += 16) {
    __syncthreads();
    {  // stage A tile 64x16 (transposed to [k][m])
      float4 v = *(const float4*)(Abase + (size_t)lm * K + k0 + lq * 4);
      As[lq * 4 + 0][lm] = v.x; As[lq * 4 + 1][lm] = v.y;
      As[lq * 4 + 2][lm] = v.z; As[lq * 4 + 3][lm] = v.w;
    }
    if (NG == 4) {  // stage W tile 256x16 -> [k][n]
      const int n = tid;
#pragma unroll
      for (int q = 0; q < 4; q++) {
        float4 v = *(const float4*)(W + (size_t)n * K + k0 + q * 4);
        Ws[q * 4 + 0][n] = v.x; Ws[q * 4 + 1][n] = v.y;
        Ws[q * 4 + 2][n] = v.z; Ws[q * 4 + 3][n] = v.w;
      }
    } else {  // BN=64
      const int n = tid & 63;
      const int q = tid >> 6;
      float4 v = *(const float4*)(W + (size_t)n * K + k0 + q * 4);
      Ws[q * 4 + 0][n] = v.x; Ws[q * 4 + 1][n] = v.y;
      Ws[q * 4 + 2][n] = v.z; Ws[q * 4 + 3][n] = v.w;
    }
    __syncthreads();
#pragma unroll
    for (int kk = 0; kk < 16; kk++) {
      float4 a4 = *(const float4*)&As[kk][ty * 4];
      float av[4] = {a4.x, a4.y, a4.z, a4.w};
#pragma unroll
      for (int g = 0; g < NG; g++) {
        float4 w4 = *(const float4*)&Ws[kk][g * 64 + tx * 4];
        float wv[4] = {w4.x, w4.y, w4.z, w4.w};
#pragma unroll
        for (int mi = 0; mi < 4; mi++)
#pragma unroll
          for (int ni = 0; ni < 4; ni++)
            acc[mi][g * 4 + ni] += av[mi] * wv[ni];
      }
    }
  }

#pragma unroll
  for (int g = 0; g < NG; g++) {
    float4 bv = *(const float4*)(bias + g * 64 + tx * 4);
    float bb[4] = {bv.x, bv.y, bv.z, bv.w};
#pragma unroll
    for (int mi = 0; mi < 4; mi++) {
      float4 o;
      float* op = (float*)&o;
#pragma unroll
      for (int ni = 0; ni < 4; ni++) {
        float v = acc[mi][g * 4 + ni] + bb[ni];
        op[ni] = TANH ? fast_tanh(v) : v;
      }
      *(float4*)(C + (size_t)(bm * 64 + ty * 4 + mi) * BN + g * 64 + tx * 4) = o;
    }
  }
}

// ---------------------------------------------------------------------------
// Serial recurrence. 16 blocks x 512 threads (8 waves). Block b owns batch
// rows [16b, 16b+16). Whh is held in VGPRs as split-bf16 (hi+lo) MFMA
// B-fragments; h lives per-owner-lane in registers (fp32) and in LDS as
// split-bf16 A-fragments. 3 MFMA passes emulate fp32: Whi*hhi + Wlo*hhi +
// Whi*hlo (residual ~2^-18). zx is read in-order and h_t (PRE-update) is
// written IN PLACE over it.
// MFMA 16x16x32 layouts (HW-verified per guide):
//   A: A[m=lane&15][k=8*(lane>>4)+i]   B: B[k=8*(lane>>4)+i][n=lane&15]
//   D: col n=lane&15, row m=4*(lane>>4)+reg
// ---------------------------------------------------------------------------
__global__ __launch_bounds__(512, 2)
void rnn_serial(float* __restrict__ zx_hall,      // [T,B,H] in: zx, out: h_all
                const float* __restrict__ Whh,    // [H,H]
                const float* __restrict__ bhh_p)  // [H]
{
  __shared__ __attribute__((aligned(16))) __bf16 hHi[16][264];
  __shared__ __attribute__((aligned(16))) __bf16 hLo[16][264];

  const int tid  = threadIdx.x;
  const int lane = tid & 63;
  const int wave = tid >> 6;   // 0..7, owns j-slice of 32
  const int l15  = lane & 15;
  const int quad = lane >> 4;  // 0..3
  const int r0   = blockIdx.x * 16;
  const int jw   = wave * 32;

  // ---- load Whh B-fragments (hi/lo bf16) into registers ----
  bf16x8 Bhi[2][8], Blo[2][8];
  int   jj[2];
  float bj[2], aj[2];
#pragma unroll
  for (int nt = 0; nt < 2; nt++) {
    jj[nt] = jw + nt * 16 + l15;
    bj[nt] = bhh_p[jj[nt]];
    aj[nt] = alpha_of(jj[nt]);
#pragma unroll
    for (int ks = 0; ks < 8; ks++) {
      const float* wp = Whh + (size_t)jj[nt] * H_DIM + ks * 32 + quad * 8;
      float4 w0 = *(const float4*)wp;
      float4 w1 = *(const float4*)(wp + 4);
      float wv[8] = {w0.x, w0.y, w0.z, w0.w, w1.x, w1.y, w1.z, w1.w};
      bf16x8 hi, lo;
#pragma unroll
      for (int i = 0; i < 8; i++) {
        float v = wv[i];
        __bf16 hb = (__bf16)v;
        hi[i] = hb;
        lo[i] = (__bf16)(v - (float)hb);
      }
      Bhi[nt][ks] = hi;
      Blo[nt][ks] = lo;
    }
  }

  // ---- init h = 0 ----
  for (int i = tid; i < 16 * 264; i += 512) {
    (&hHi[0][0])[i] = (__bf16)0.0f;
    (&hLo[0][0])[i] = (__bf16)0.0f;
  }
  __syncthreads();

  // per-lane fp32 h state for owned (r,j) cells
  float hreg[2][4];
#pragma unroll
  for (int nt = 0; nt < 2; nt++)
#pragma unroll
    for (int rg = 0; rg < 4; rg++) hreg[nt][rg] = 0.0f;

  // prefetch zx for t=0
  float zc[2][4];
#pragma unroll
  for (int nt = 0; nt < 2; nt++)
#pragma unroll
    for (int rg = 0; rg < 4; rg++)
      zc[nt][rg] = zx_hall[((size_t)(r0 + quad * 4 + rg)) * H_DIM + jj[nt]];

  for (int t = 0; t < T_LEN; t++) {
    // ---- D = h @ Whh^T via split-bf16 MFMA ----
    f32x4 acc0 = {0.0f, 0.0f, 0.0f, 0.0f};
    f32x4 acc1 = {0.0f, 0.0f, 0.0f, 0.0f};
#pragma unroll
    for (int ks = 0; ks < 8; ks++) {
      bf16x8 ahi = *(const bf16x8*)&hHi[l15][ks * 32 + quad * 8];
      bf16x8 alo = *(const bf16x8*)&hLo[l15][ks * 32 + quad * 8];
      acc0 = __builtin_amdgcn_mfma_f32_16x16x32_bf16(ahi, Bhi[0][ks], acc0, 0, 0, 0);
      acc1 = __builtin_amdgcn_mfma_f32_16x16x32_bf16(ahi, Bhi[1][ks], acc1, 0, 0, 0);
      acc0 = __builtin_amdgcn_mfma_f32_16x16x32_bf16(alo, Bhi[0][ks], acc0, 0, 0, 0);
      acc1 = __builtin_amdgcn_mfma_f32_16x16x32_bf16(alo, Bhi[1][ks], acc1, 0, 0, 0);
      acc0 = __builtin_amdgcn_mfma_f32_16x16x32_bf16(ahi, Blo[0][ks], acc0, 0, 0, 0);
      acc1 = __builtin_amdgcn_mfma_f32_16x16x32_bf16(ahi, Blo[1][ks], acc1, 0, 0, 0);
    }

    // prefetch next step's zx (hides HBM latency behind this step's tail)
    float zn[2][4] = {{0.f, 0.f, 0.f, 0.f}, {0.f, 0.f, 0.f, 0.f}};
    if (t + 1 < T_LEN) {
#pragma unroll
      for (int nt = 0; nt < 2; nt++)
#pragma unroll
        for (int rg = 0; rg < 4; rg++)
          zn[nt][rg] = zx_hall[((size_t)(t + 1) * B_SZ + r0 + quad * 4 + rg) * H_DIM + jj[nt]];
    }

    // ---- epilogue: y-state store (pre-update h), alpha blend ----
    float hnew[2][4];
#pragma unroll
    for (int nt = 0; nt < 2; nt++) {
      const f32x4 acc = nt ? acc1 : acc0;
#pragma unroll
      for (int rg = 0; rg < 4; rg++) {
        const int r = quad * 4 + rg;
        float ho = hreg[nt][rg];
        float hr = fast_tanh(zc[nt][rg] + acc[rg] + bj[nt]);
        hnew[nt][rg] = (1.0f - aj[nt]) * ho + aj[nt] * hr;
        // h_all[t] = PRE-update h_t, written over consumed zx[t]
        zx_hall[((size_t)t * B_SZ + r0 + r) * H_DIM + jj[nt]] = ho;
      }
    }

    __syncthreads();  // all waves done reading hHi/hLo A-frags
#pragma unroll
    for (int nt = 0; nt < 2; nt++) {
#pragma unroll
      for (int rg = 0; rg < 4; rg++) {
        const int r = quad * 4 + rg;
        float hn = hnew[nt][rg];
        hreg[nt][rg] = hn;
        __bf16 hb = (__bf16)hn;
        hHi[r][jj[nt]] = hb;
        hLo[r][jj[nt]] = (__bf16)(hn - (float)hb);
      }
    }
    __syncthreads();  // h published for next step

#pragma unroll
    for (int nt = 0; nt < 2; nt++)
#pragma unroll
      for (int rg = 0; rg < 4; rg++) zc[nt][rg] = zn[nt][rg];
  }
}

// ---------------------------------------------------------------------------
extern "C" void kernel_launch(void* const* d_in, const int* in_sizes, int n_in,
                              void* d_out, int out_size, void* d_ws, size_t ws_size,
                              hipStream_t stream) {
  const float* x   = (const float*)d_in[0];
  const float* Wx0 = (const float*)d_in[1];
  const float* bx0 = (const float*)d_in[2];
  const float* Wx1 = (const float*)d_in[3];
  const float* bx1 = (const float*)d_in[4];
  const float* Wih = (const float*)d_in[5];
  const float* Whh = (const float*)d_in[6];
  const float* bih = (const float*)d_in[7];
  const float* bhh = (const float*)d_in[8];
  const float* Wh0 = (const float*)d_in[9];
  const float* bh0 = (const float*)d_in[10];
  const float* Wh1 = (const float*)d_in[11];
  const float* bh1 = (const float*)d_in[12];
  const float* Wg  = (const float*)d_in[13];
  const float* bg  = (const float*)d_in[14];
  float* out = (float*)d_out;

  // single scratch buffer: 262144*256 floats = 256 MB (ws_size must cover it)
  float* buf = (float*)d_ws;

  dim3 grid(M_ROWS / 64), block(256);
  // 1) buf = tanh(x Wx0^T + bx0)            K=64
  gemm_bias_act<4, true><<<grid, block, 0, stream>>>(x, Wx0, bx0, buf, 64);
  // 2) buf = tanh(buf Wx1^T + bx1)          K=256, in-place
  gemm_bias_act<4, true><<<grid, block, 0, stream>>>(buf, Wx1, bx1, buf, 256);
  // 3) buf = buf Wih^T + bih  (= zx)        K=256, in-place
  gemm_bias_act<4, false><<<grid, block, 0, stream>>>(buf, Wih, bih, buf, 256);
  // 4) serial recurrence (in place: zx -> h_all)
  rnn_serial<<<dim3(16), dim3(512), 0, stream>>>(buf, Whh, bhh);
  // 5) buf = tanh(buf Wh0^T + bh0)          in-place
  gemm_bias_act<4, true><<<grid, block, 0, stream>>>(buf, Wh0, bh0, buf, 256);
  // 6) buf = tanh(buf Wh1^T + bh1)          in-place
  gemm_bias_act<4, true><<<grid, block, 0, stream>>>(buf, Wh1, bh1, buf, 256);
  // 7) out = buf Wg^T + bg
  gemm_bias_act<1, false><<<grid, block, 0, stream>>>(buf, Wg, bg, out, 256);
}

// Round 3
// 2012.226 us; speedup vs baseline: 1.9866x; 1.9866x over previous
//
#include <hip/hip_runtime.h>
#include <cstddef>

// ---------------------------------------------------------------------------
// MT_RNN: y_t = MLP(h_t);  h_{t+1} = (1-a) h_t + a tanh(zx_t + h_t Whh^T + bhh)
// Single 256 MB scratch buffer, all-MFMA pipeline:
//   1) buf = tanh(x Wx0^T + bx0)        gemm_mfma8<KCH=2>
//   2) buf = tanh(buf Wx1^T + bx1)      gemm_mfma8<KCH=8>  (in-place)
//   3) buf = buf Wih^T + bih (= zx)     gemm_mfma8<KCH=8>  (in-place)
//   4) serial recurrence, h_t over consumed zx[t] (in-place), 16 CUs
//   5) buf = tanh(buf Wh0^T + bh0)      gemm_mfma8<KCH=8>  (in-place)
//   6) buf = tanh(buf Wh1^T + bh1)      gemm_mfma8<KCH=8>  (in-place)
//   7) out = buf Wg^T + bg              gemm_mfma4_out
// Precision scheme: W always split exact (hi+lo bf16); activations:
//   - bulk GEMMs: A split hi/lo, 3 MFMA passes (drop lo*lo ~ 2^-18)
//   - serial: h plain bf16 (random per-step noise, damped by leaky blend),
//     2 MFMA passes; blend itself in exact fp32 registers.
// ---------------------------------------------------------------------------

typedef __bf16 bf16x8 __attribute__((ext_vector_type(8)));
typedef __bf16 bf16x4 __attribute__((ext_vector_type(4)));
typedef float  f32x4  __attribute__((ext_vector_type(4)));

#define T_LEN 1024
#define B_SZ  256
#define H_DIM 256
#define M_ROWS (T_LEN * B_SZ)  // 262144

__device__ __forceinline__ float fast_tanh(float x) {
  float e = __expf(2.0f * x);
  return 1.0f - 2.0f / (e + 1.0f);
}

// sorted alpha assignment over 256 units: 86 x 0.001, 85 x 0.01, 85 x 0.1
__device__ __forceinline__ float alpha_of(int j) {
  return (j < 86) ? 0.001f : ((j < 171) ? 0.01f : 0.1f);
}

// barrier with LDS-only drain: no vmcnt(0) — global loads/stores stay in
// flight across it (the m97-style barrier-drain stall is the thing we kill).
__device__ __forceinline__ void lds_barrier() {
  asm volatile("s_waitcnt lgkmcnt(0)\n\ts_barrier" ::: "memory");
}

// ---------------------------------------------------------------------------
// MFMA GEMM, 8 waves (512 thr), N = 256 fixed, M-tile = 32 rows, grid-stride.
// W fragments (hi+lo) register-resident per wave (wave owns 32 columns).
// A staged per tile as bf16 hi/lo in LDS (33.8 KB). 3 MFMA passes.
// In-place safe (A==C): block reads only its own rows (staging, before
// barrier), writes only its own rows (epilogue); tiles are block-exclusive.
// MFMA 16x16x32 layouts (HW-verified in round-2's passing rnn_serial):
//   A: A[m=lane&15][k=8*(lane>>4)+i]   B: B[k=8*(lane>>4)+i][n=lane&15]
//   D: col n=lane&15, row m=4*(lane>>4)+reg
// ---------------------------------------------------------------------------
template <int KCH, bool TANH>
__global__ __launch_bounds__(512, 2)
void gemm_mfma8(const float* A, const float* __restrict__ W,
                const float* __restrict__ bias, float* C, int mtiles) {
  constexpr int K  = KCH * 32;
  constexpr int KP = K + 8;  // row stride 4 dwords mod 32 -> 2-way (free)
  __shared__ __attribute__((aligned(16))) __bf16 Ahi[32][KP];
  __shared__ __attribute__((aligned(16))) __bf16 Alo[32][KP];

  const int tid  = threadIdx.x;
  const int lane = tid & 63;
  const int wave = tid >> 6;   // 0..7, owns 32 output columns
  const int l15  = lane & 15;
  const int quad = lane >> 4;
  const int jw   = wave * 32;

  // ---- register-resident W fragments (hi/lo) ----
  bf16x8 Bhi[2][KCH], Blo[2][KCH];
  float  bcol[2];
  int    jj[2];
#pragma unroll
  for (int nt = 0; nt < 2; nt++) {
    jj[nt]   = jw + nt * 16 + l15;
    bcol[nt] = bias[jj[nt]];
#pragma unroll
    for (int ks = 0; ks < KCH; ks++) {
      const float* wp = W + (size_t)jj[nt] * K + ks * 32 + quad * 8;
      float4 w0 = *(const float4*)wp;
      float4 w1 = *(const float4*)(wp + 4);
      float wv[8] = {w0.x, w0.y, w0.z, w0.w, w1.x, w1.y, w1.z, w1.w};
      bf16x8 hi, lo;
#pragma unroll
      for (int i = 0; i < 8; i++) {
        float v = wv[i];
        __bf16 hb = (__bf16)v;
        hi[i] = hb;
        lo[i] = (__bf16)(v - (float)hb);
      }
      Bhi[nt][ks] = hi;
      Blo[nt][ks] = lo;
    }
  }

  // staging map: 16 threads per row, 32 rows; coalesced 256B segments
  const int srow = tid >> 4;            // 0..31
  const int sk4  = tid & 15;            // float4 column base
  constexpr int SEG = K / 64;           // float4s per thread (K=256->4, 64->1)

  for (int bm = blockIdx.x; bm < mtiles; bm += gridDim.x) {
    const float* Ab = A + (size_t)bm * 32 * K;
    float4 tv[SEG];
#pragma unroll
    for (int s = 0; s < SEG; s++)
      tv[s] = *(const float4*)(Ab + (size_t)srow * K + (sk4 + s * 16) * 4);
#pragma unroll
    for (int s = 0; s < SEG; s++) {
      float vv[4] = {tv[s].x, tv[s].y, tv[s].z, tv[s].w};
      bf16x4 hi, lo;
#pragma unroll
      for (int i = 0; i < 4; i++) {
        __bf16 hb = (__bf16)vv[i];
        hi[i] = hb;
        lo[i] = (__bf16)(vv[i] - (float)hb);
      }
      const int k = (sk4 + s * 16) * 4;
      *(bf16x4*)&Ahi[srow][k] = hi;
      *(bf16x4*)&Alo[srow][k] = lo;
    }
    lds_barrier();

    f32x4 acc[2][2];
#pragma unroll
    for (int mi = 0; mi < 2; mi++)
#pragma unroll
      for (int nt = 0; nt < 2; nt++) acc[mi][nt] = (f32x4){0.f, 0.f, 0.f, 0.f};

#pragma unroll
    for (int ks = 0; ks < KCH; ks++) {
#pragma unroll
      for (int mi = 0; mi < 2; mi++) {
        bf16x8 ahi = *(const bf16x8*)&Ahi[mi * 16 + l15][ks * 32 + quad * 8];
        bf16x8 alo = *(const bf16x8*)&Alo[mi * 16 + l15][ks * 32 + quad * 8];
#pragma unroll
        for (int nt = 0; nt < 2; nt++) {
          acc[mi][nt] = __builtin_amdgcn_mfma_f32_16x16x32_bf16(ahi, Bhi[nt][ks], acc[mi][nt], 0, 0, 0);
          acc[mi][nt] = __builtin_amdgcn_mfma_f32_16x16x32_bf16(alo, Bhi[nt][ks], acc[mi][nt], 0, 0, 0);
          acc[mi][nt] = __builtin_amdgcn_mfma_f32_16x16x32_bf16(ahi, Blo[nt][ks], acc[mi][nt], 0, 0, 0);
        }
      }
    }

    // epilogue (no LDS): bias + act + scalar stores (16-lane 64B segments)
#pragma unroll
    for (int mi = 0; mi < 2; mi++)
#pragma unroll
      for (int nt = 0; nt < 2; nt++)
#pragma unroll
        for (int rg = 0; rg < 4; rg++) {
          const int rowg = bm * 32 + mi * 16 + quad * 4 + rg;
          float v = acc[mi][nt][rg] + bcol[nt];
          if (TANH) v = fast_tanh(v);
          C[(size_t)rowg * 256 + jj[nt]] = v;
        }
    lds_barrier();  // compute reads done before next tile's staging writes
  }
}

// ---------------------------------------------------------------------------
// Final projection: out[M,64] = buf[M,256] @ Wg[64,256]^T + bg.
// 4 waves (256 thr), wave owns 16 columns; M-tile 32; different out buffer
// (no aliasing). 3-pass split as above.
// ---------------------------------------------------------------------------
__global__ __launch_bounds__(256, 2)
void gemm_mfma4_out(const float* __restrict__ A, const float* __restrict__ W,
                    const float* __restrict__ bias, float* __restrict__ C,
                    int mtiles) {
  constexpr int K = 256, KCH = 8, KP = 264;
  __shared__ __attribute__((aligned(16))) __bf16 Ahi[32][KP];
  __shared__ __attribute__((aligned(16))) __bf16 Alo[32][KP];

  const int tid  = threadIdx.x;
  const int lane = tid & 63;
  const int wave = tid >> 6;   // 0..3
  const int l15  = lane & 15;
  const int quad = lane >> 4;
  const int jcol = wave * 16 + l15;

  bf16x8 Bhi[KCH], Blo[KCH];
  const float bc = bias[jcol];
#pragma unroll
  for (int ks = 0; ks < KCH; ks++) {
    const float* wp = W + (size_t)jcol * K + ks * 32 + quad * 8;
    float4 w0 = *(const float4*)wp;
    float4 w1 = *(const float4*)(wp + 4);
    float wv[8] = {w0.x, w0.y, w0.z, w0.w, w1.x, w1.y, w1.z, w1.w};
    bf16x8 hi, lo;
#pragma unroll
    for (int i = 0; i < 8; i++) {
      float v = wv[i];
      __bf16 hb = (__bf16)v;
      hi[i] = hb;
      lo[i] = (__bf16)(v - (float)hb);
    }
    Bhi[ks] = hi;
    Blo[ks] = lo;
  }

  const int srow = tid >> 3;  // 0..31, 8 thr/row
  const int sk4  = tid & 7;

  for (int bm = blockIdx.x; bm < mtiles; bm += gridDim.x) {
    const float* Ab = A + (size_t)bm * 32 * K;
    float4 tv[8];
#pragma unroll
    for (int s = 0; s < 8; s++)
      tv[s] = *(const float4*)(Ab + (size_t)srow * K + (sk4 + s * 8) * 4);
#pragma unroll
    for (int s = 0; s < 8; s++) {
      float vv[4] = {tv[s].x, tv[s].y, tv[s].z, tv[s].w};
      bf16x4 hi, lo;
#pragma unroll
      for (int i = 0; i < 4; i++) {
        __bf16 hb = (__bf16)vv[i];
        hi[i] = hb;
        lo[i] = (__bf16)(vv[i] - (float)hb);
      }
      const int k = (sk4 + s * 8) * 4;
      *(bf16x4*)&Ahi[srow][k] = hi;
      *(bf16x4*)&Alo[srow][k] = lo;
    }
    lds_barrier();

    f32x4 acc[2];
#pragma unroll
    for (int mi = 0; mi < 2; mi++) acc[mi] = (f32x4){0.f, 0.f, 0.f, 0.f};
#pragma unroll
    for (int ks = 0; ks < KCH; ks++)
#pragma unroll
      for (int mi = 0; mi < 2; mi++) {
        bf16x8 ahi = *(const bf16x8*)&Ahi[mi * 16 + l15][ks * 32 + quad * 8];
        bf16x8 alo = *(const bf16x8*)&Alo[mi * 16 + l15][ks * 32 + quad * 8];
        acc[mi] = __builtin_amdgcn_mfma_f32_16x16x32_bf16(ahi, Bhi[ks], acc[mi], 0, 0, 0);
        acc[mi] = __builtin_amdgcn_mfma_f32_16x16x32_bf16(alo, Bhi[ks], acc[mi], 0, 0, 0);
        acc[mi] = __builtin_amdgcn_mfma_f32_16x16x32_bf16(ahi, Blo[ks], acc[mi], 0, 0, 0);
      }

#pragma unroll
    for (int mi = 0; mi < 2; mi++)
#pragma unroll
      for (int rg = 0; rg < 4; rg++) {
        const int rowg = bm * 32 + mi * 16 + quad * 4 + rg;
        C[(size_t)rowg * 64 + jcol] = acc[mi][rg] + bc;
      }
    lds_barrier();
  }
}

// ---------------------------------------------------------------------------
// Serial recurrence. 16 blocks x 512 threads; block owns 16 batch rows.
// Changes vs round 2: (1) 2-pass MFMA (W hi/lo exact, h plain bf16 — random
// per-step rounding noise is damped by the leaky blend; blend state stays
// fp32 in registers); (2) double-buffered h in LDS -> ONE barrier per step;
// (3) lds_barrier (lgkmcnt-only) so the zx prefetch and h_t stores stay in
// flight across the barrier (no vmcnt(0) drain).
// ---------------------------------------------------------------------------
__global__ __launch_bounds__(512, 2)
void rnn_serial(float* __restrict__ zx_hall,      // [T,B,H] in: zx, out: h_all
                const float* __restrict__ Whh,    // [H,H]
                const float* __restrict__ bhh_p)  // [H]
{
  __shared__ __attribute__((aligned(16))) __bf16 hB[2][16][264];

  const int tid  = threadIdx.x;
  const int lane = tid & 63;
  const int wave = tid >> 6;   // 0..7, owns 32 columns
  const int l15  = lane & 15;
  const int quad = lane >> 4;
  const int r0   = blockIdx.x * 16;
  const int jw   = wave * 32;

  // ---- Whh B-fragments, exact split hi+lo ----
  bf16x8 Bhi[2][8], Blo[2][8];
  int   jj[2];
  float bj[2], aj[2], oma[2];
#pragma unroll
  for (int nt = 0; nt < 2; nt++) {
    jj[nt]  = jw + nt * 16 + l15;
    bj[nt]  = bhh_p[jj[nt]];
    aj[nt]  = alpha_of(jj[nt]);
    oma[nt] = 1.0f - aj[nt];
#pragma unroll
    for (int ks = 0; ks < 8; ks++) {
      const float* wp = Whh + (size_t)jj[nt] * H_DIM + ks * 32 + quad * 8;
      float4 w0 = *(const float4*)wp;
      float4 w1 = *(const float4*)(wp + 4);
      float wv[8] = {w0.x, w0.y, w0.z, w0.w, w1.x, w1.y, w1.z, w1.w};
      bf16x8 hi, lo;
#pragma unroll
      for (int i = 0; i < 8; i++) {
        float v = wv[i];
        __bf16 hb = (__bf16)v;
        hi[i] = hb;
        lo[i] = (__bf16)(v - (float)hb);
      }
      Bhi[nt][ks] = hi;
      Blo[nt][ks] = lo;
    }
  }

  // ---- init h buffer 0 = 0 ----
  for (int i = tid; i < 16 * 264; i += 512) (&hB[0][0][0])[i] = (__bf16)0.0f;
  __syncthreads();

  // fp32 state + fixed global offsets (advance by B*H per step)
  float  hreg[2][4];
  size_t zoff[2][4];
  float  zc[2][4];
#pragma unroll
  for (int nt = 0; nt < 2; nt++)
#pragma unroll
    for (int rg = 0; rg < 4; rg++) {
      hreg[nt][rg] = 0.0f;
      zoff[nt][rg] = (size_t)(r0 + quad * 4 + rg) * H_DIM + jj[nt];
      zc[nt][rg]   = zx_hall[zoff[nt][rg]];  // t = 0
    }

  int p = 0;
  for (int t = 0; t < T_LEN; t++) {
    // ---- z = h @ Whh^T, 2-pass split-W MFMA, 4 independent chains ----
    f32x4 aH0 = {0.f, 0.f, 0.f, 0.f}, aH1 = {0.f, 0.f, 0.f, 0.f};
    f32x4 aL0 = {0.f, 0.f, 0.f, 0.f}, aL1 = {0.f, 0.f, 0.f, 0.f};
#pragma unroll
    for (int ks = 0; ks < 8; ks++) {
      bf16x8 a = *(const bf16x8*)&hB[p][l15][ks * 32 + quad * 8];
      aH0 = __builtin_amdgcn_mfma_f32_16x16x32_bf16(a, Bhi[0][ks], aH0, 0, 0, 0);
      aH1 = __builtin_amdgcn_mfma_f32_16x16x32_bf16(a, Bhi[1][ks], aH1, 0, 0, 0);
      aL0 = __builtin_amdgcn_mfma_f32_16x16x32_bf16(a, Blo[0][ks], aL0, 0, 0, 0);
      aL1 = __builtin_amdgcn_mfma_f32_16x16x32_bf16(a, Blo[1][ks], aL1, 0, 0, 0);
    }

    // prefetch next zx (clamped at the end; stale value unused)
    const size_t tb = (size_t)((t + 1 < T_LEN) ? t + 1 : t) * (B_SZ * H_DIM);
    float zn[2][4];
#pragma unroll
    for (int nt = 0; nt < 2; nt++)
#pragma unroll
      for (int rg = 0; rg < 4; rg++) zn[nt][rg] = zx_hall[tb + zoff[nt][rg]];

    // ---- epilogue: store pre-update h_t, fp32 alpha blend, publish bf16 h ----
    const size_t tcur = (size_t)t * (B_SZ * H_DIM);
#pragma unroll
    for (int nt = 0; nt < 2; nt++) {
      const f32x4 zh = nt ? aH1 : aH0;
      const f32x4 zl = nt ? aL1 : aL0;
#pragma unroll
      for (int rg = 0; rg < 4; rg++) {
        const int r = quad * 4 + rg;
        float ho = hreg[nt][rg];
        float hr = fast_tanh(zc[nt][rg] + zh[rg] + zl[rg] + bj[nt]);
        float hn = oma[nt] * ho + aj[nt] * hr;
        zx_hall[tcur + zoff[nt][rg]] = ho;       // h_all[t] = pre-update h
        hreg[nt][rg] = hn;
        hB[p ^ 1][r][jj[nt]] = (__bf16)hn;       // next step's A operand
      }
    }

    lds_barrier();  // lgkm-only: global prefetch/stores stay in flight
    p ^= 1;
#pragma unroll
    for (int nt = 0; nt < 2; nt++)
#pragma unroll
      for (int rg = 0; rg < 4; rg++) zc[nt][rg] = zn[nt][rg];
  }
}

// ---------------------------------------------------------------------------
extern "C" void kernel_launch(void* const* d_in, const int* in_sizes, int n_in,
                              void* d_out, int out_size, void* d_ws, size_t ws_size,
                              hipStream_t stream) {
  const float* x   = (const float*)d_in[0];
  const float* Wx0 = (const float*)d_in[1];
  const float* bx0 = (const float*)d_in[2];
  const float* Wx1 = (const float*)d_in[3];
  const float* bx1 = (const float*)d_in[4];
  const float* Wih = (const float*)d_in[5];
  const float* Whh = (const float*)d_in[6];
  const float* bih = (const float*)d_in[7];
  const float* bhh = (const float*)d_in[8];
  const float* Wh0 = (const float*)d_in[9];
  const float* bh0 = (const float*)d_in[10];
  const float* Wh1 = (const float*)d_in[11];
  const float* bh1 = (const float*)d_in[12];
  const float* Wg  = (const float*)d_in[13];
  const float* bg  = (const float*)d_in[14];
  float* out = (float*)d_out;

  float* buf = (float*)d_ws;  // 262144*256 floats = 256 MB
  const int MT = M_ROWS / 32; // 8192 m-tiles of 32 rows

  // 1) buf = tanh(x Wx0^T + bx0)        K=64
  gemm_mfma8<2, true><<<512, 512, 0, stream>>>(x, Wx0, bx0, buf, MT);
  // 2) buf = tanh(buf Wx1^T + bx1)      in-place
  gemm_mfma8<8, true><<<512, 512, 0, stream>>>(buf, Wx1, bx1, buf, MT);
  // 3) buf = buf Wih^T + bih (= zx)     in-place
  gemm_mfma8<8, false><<<512, 512, 0, stream>>>(buf, Wih, bih, buf, MT);
  // 4) serial recurrence (in place: zx -> h_all)
  rnn_serial<<<16, 512, 0, stream>>>(buf, Whh, bhh);
  // 5) buf = tanh(buf Wh0^T + bh0)      in-place
  gemm_mfma8<8, true><<<512, 512, 0, stream>>>(buf, Wh0, bh0, buf, MT);
  // 6) buf = tanh(buf Wh1^T + bh1)      in-place
  gemm_mfma8<8, true><<<512, 512, 0, stream>>>(buf, Wh1, bh1, buf, MT);
  // 7) out = buf Wg^T + bg
  gemm_mfma4_out<<<512, 256, 0, stream>>>(buf, Wg, bg, out, MT);
}

// Round 4
// 1630.215 us; speedup vs baseline: 2.4522x; 1.2343x over previous
//
#include <hip/hip_runtime.h>
#include <cstddef>

// ---------------------------------------------------------------------------
// MT_RNN: y_t = MLP(h_t);  h_{t+1} = (1-a) h_t + a tanh(zx_t + h_t Whh^T + bhh)
// Round 4: all-fp16 single-pass MFMA (fp16 5e-4 rel err beats 2/3-pass bf16
// splits AND cuts MFMA count 2-3x; every tensor is range-bounded so fp16 is
// safe). Serial kernel widened to 16 waves (4/SIMD) for latency hiding.
//   1) buf = tanh(x Wx0^T + bx0)        gemm_f16<KCH=2>
//   2) buf = tanh(buf Wx1^T + bx1)      gemm_f16<KCH=8>  (in-place)
//   3) buf = buf Wih^T + bih (= zx)     gemm_f16<KCH=8>  (in-place)
//   4) serial recurrence, h_t over consumed zx[t] (in-place), 16 CUs
//   5) buf = tanh(buf Wh0^T + bh0)      gemm_f16<KCH=8>  (in-place)
//   6) buf = tanh(buf Wh1^T + bh1)      gemm_f16<KCH=8>  (in-place)
//   7) out = buf Wg^T + bg              gemm_f16_out
// ws requirement: 262144*256*4 = 256 MB.
// ---------------------------------------------------------------------------

typedef _Float16 halfx8 __attribute__((ext_vector_type(8)));
typedef _Float16 halfx4 __attribute__((ext_vector_type(4)));
typedef float    f32x4  __attribute__((ext_vector_type(4)));

#define T_LEN 1024
#define B_SZ  256
#define H_DIM 256
#define M_ROWS (T_LEN * B_SZ)  // 262144

__device__ __forceinline__ float fast_tanh(float x) {
  float e = __expf(2.0f * x);
  return 1.0f - 2.0f / (e + 1.0f);
}

// sorted alpha assignment over 256 units: 86 x 0.001, 85 x 0.01, 85 x 0.1
__device__ __forceinline__ float alpha_of(int j) {
  return (j < 86) ? 0.001f : ((j < 171) ? 0.01f : 0.1f);
}

// barrier with LDS-only drain: global loads/stores stay in flight across it
__device__ __forceinline__ void lds_barrier() {
  asm volatile("s_waitcnt lgkmcnt(0)\n\ts_barrier" ::: "memory");
}

// ---------------------------------------------------------------------------
// fp16 single-pass MFMA GEMM. 8 waves, N=256, M-tile=32, grid-stride.
// W fragments register-resident (wave owns 32 cols); A staged fp16 in LDS.
// In-place safe (block reads only its own rows before writing them).
// MFMA 16x16x32 layouts (HW-verified rounds 2-3):
//   A: A[m=lane&15][k=8*(lane>>4)+i]   B: B[k=8*(lane>>4)+i][n=lane&15]
//   D: col n=lane&15, row m=4*(lane>>4)+reg
// ---------------------------------------------------------------------------
template <int KCH, bool TANH>
__global__ __launch_bounds__(512, 2)
void gemm_f16(const float* A, const float* __restrict__ W,
              const float* __restrict__ bias, float* C, int mtiles) {
  constexpr int K  = KCH * 32;
  constexpr int KP = K + 8;
  __shared__ __attribute__((aligned(16))) _Float16 Ah[32][KP];

  const int tid  = threadIdx.x;
  const int lane = tid & 63;
  const int wave = tid >> 6;   // 0..7, owns 32 output columns
  const int l15  = lane & 15;
  const int quad = lane >> 4;
  const int jw   = wave * 32;

  // register-resident W fragments (fp16)
  halfx8 Bf[2][KCH];
  float  bcol[2];
  int    jj[2];
#pragma unroll
  for (int nt = 0; nt < 2; nt++) {
    jj[nt]   = jw + nt * 16 + l15;
    bcol[nt] = bias[jj[nt]];
#pragma unroll
    for (int ks = 0; ks < KCH; ks++) {
      const float* wp = W + (size_t)jj[nt] * K + ks * 32 + quad * 8;
      float4 w0 = *(const float4*)wp;
      float4 w1 = *(const float4*)(wp + 4);
      halfx8 f;
      f[0] = (_Float16)w0.x; f[1] = (_Float16)w0.y;
      f[2] = (_Float16)w0.z; f[3] = (_Float16)w0.w;
      f[4] = (_Float16)w1.x; f[5] = (_Float16)w1.y;
      f[6] = (_Float16)w1.z; f[7] = (_Float16)w1.w;
      Bf[nt][ks] = f;
    }
  }

  const int srow = tid >> 4;   // 0..31
  const int sk4  = tid & 15;   // float4 column base
  constexpr int SEG = K / 64;  // float4s per thread

  for (int bm = blockIdx.x; bm < mtiles; bm += gridDim.x) {
    const float* Ab = A + (size_t)bm * 32 * K;
    float4 tv[SEG];
#pragma unroll
    for (int s = 0; s < SEG; s++)
      tv[s] = *(const float4*)(Ab + (size_t)srow * K + (sk4 + s * 16) * 4);
#pragma unroll
    for (int s = 0; s < SEG; s++) {
      halfx4 h;
      h[0] = (_Float16)tv[s].x; h[1] = (_Float16)tv[s].y;
      h[2] = (_Float16)tv[s].z; h[3] = (_Float16)tv[s].w;
      *(halfx4*)&Ah[srow][(sk4 + s * 16) * 4] = h;
    }
    lds_barrier();

    f32x4 acc[2][2];
#pragma unroll
    for (int mi = 0; mi < 2; mi++)
#pragma unroll
      for (int nt = 0; nt < 2; nt++) acc[mi][nt] = (f32x4){0.f, 0.f, 0.f, 0.f};

#pragma unroll
    for (int ks = 0; ks < KCH; ks++)
#pragma unroll
      for (int mi = 0; mi < 2; mi++) {
        halfx8 a = *(const halfx8*)&Ah[mi * 16 + l15][ks * 32 + quad * 8];
#pragma unroll
        for (int nt = 0; nt < 2; nt++)
          acc[mi][nt] = __builtin_amdgcn_mfma_f32_16x16x32_f16(a, Bf[nt][ks], acc[mi][nt], 0, 0, 0);
      }

#pragma unroll
    for (int mi = 0; mi < 2; mi++)
#pragma unroll
      for (int nt = 0; nt < 2; nt++)
#pragma unroll
        for (int rg = 0; rg < 4; rg++) {
          const int rowg = bm * 32 + mi * 16 + quad * 4 + rg;
          float v = acc[mi][nt][rg] + bcol[nt];
          if (TANH) v = fast_tanh(v);
          C[(size_t)rowg * 256 + jj[nt]] = v;
        }
    lds_barrier();  // MFMA reads done before next tile's staging writes
  }
}

// ---------------------------------------------------------------------------
// Final projection: out[M,64] = buf[M,256] @ Wg[64,256]^T + bg. 4 waves.
// ---------------------------------------------------------------------------
__global__ __launch_bounds__(256, 2)
void gemm_f16_out(const float* __restrict__ A, const float* __restrict__ W,
                  const float* __restrict__ bias, float* __restrict__ C,
                  int mtiles) {
  constexpr int K = 256, KCH = 8, KP = 264;
  __shared__ __attribute__((aligned(16))) _Float16 Ah[32][KP];

  const int tid  = threadIdx.x;
  const int lane = tid & 63;
  const int wave = tid >> 6;   // 0..3
  const int l15  = lane & 15;
  const int quad = lane >> 4;
  const int jcol = wave * 16 + l15;

  halfx8 Bf[KCH];
  const float bc = bias[jcol];
#pragma unroll
  for (int ks = 0; ks < KCH; ks++) {
    const float* wp = W + (size_t)jcol * K + ks * 32 + quad * 8;
    float4 w0 = *(const float4*)wp;
    float4 w1 = *(const float4*)(wp + 4);
    halfx8 f;
    f[0] = (_Float16)w0.x; f[1] = (_Float16)w0.y;
    f[2] = (_Float16)w0.z; f[3] = (_Float16)w0.w;
    f[4] = (_Float16)w1.x; f[5] = (_Float16)w1.y;
    f[6] = (_Float16)w1.z; f[7] = (_Float16)w1.w;
    Bf[ks] = f;
  }

  const int srow = tid >> 3;  // 0..31, 8 thr/row
  const int sk4  = tid & 7;

  for (int bm = blockIdx.x; bm < mtiles; bm += gridDim.x) {
    const float* Ab = A + (size_t)bm * 32 * K;
    float4 tv[8];
#pragma unroll
    for (int s = 0; s < 8; s++)
      tv[s] = *(const float4*)(Ab + (size_t)srow * K + (sk4 + s * 8) * 4);
#pragma unroll
    for (int s = 0; s < 8; s++) {
      halfx4 h;
      h[0] = (_Float16)tv[s].x; h[1] = (_Float16)tv[s].y;
      h[2] = (_Float16)tv[s].z; h[3] = (_Float16)tv[s].w;
      *(halfx4*)&Ah[srow][(sk4 + s * 8) * 4] = h;
    }
    lds_barrier();

    f32x4 acc[2];
#pragma unroll
    for (int mi = 0; mi < 2; mi++) acc[mi] = (f32x4){0.f, 0.f, 0.f, 0.f};
#pragma unroll
    for (int ks = 0; ks < KCH; ks++)
#pragma unroll
      for (int mi = 0; mi < 2; mi++) {
        halfx8 a = *(const halfx8*)&Ah[mi * 16 + l15][ks * 32 + quad * 8];
        acc[mi] = __builtin_amdgcn_mfma_f32_16x16x32_f16(a, Bf[ks], acc[mi], 0, 0, 0);
      }

#pragma unroll
    for (int mi = 0; mi < 2; mi++)
#pragma unroll
      for (int rg = 0; rg < 4; rg++) {
        const int rowg = bm * 32 + mi * 16 + quad * 4 + rg;
        C[(size_t)rowg * 64 + jcol] = acc[mi][rg] + bc;
      }
    lds_barrier();
  }
}

// ---------------------------------------------------------------------------
// Serial recurrence. 16 blocks x 1024 threads (16 waves, 4/SIMD). Block owns
// 16 batch rows; wave owns 16 h-columns (one n-tile). fp16 single-pass MFMA
// (z error ~3e-4/step, better than round-3's 2-pass bf16). h blend state in
// fp32 registers; h published to LDS as fp16 A-fragments, double-buffered,
// ONE lgkm-only barrier per step (zx prefetch + h_t stores stay in flight).
// ---------------------------------------------------------------------------
__global__ __launch_bounds__(1024, 4)
void rnn_serial(float* __restrict__ zx_hall,      // [T,B,H] in: zx, out: h_all
                const float* __restrict__ Whh,    // [H,H]
                const float* __restrict__ bhh_p)  // [H]
{
  __shared__ __attribute__((aligned(16))) _Float16 hB[2][16][264];

  const int tid  = threadIdx.x;
  const int lane = tid & 63;
  const int wave = tid >> 6;   // 0..15, owns 16 columns
  const int l15  = lane & 15;
  const int quad = lane >> 4;
  const int r0   = blockIdx.x * 16;
  const int jcol = wave * 16 + l15;

  // Whh B-fragments (fp16): B[k][n=jcol] = Whh[jcol][k]
  halfx8 Bf[8];
#pragma unroll
  for (int ks = 0; ks < 8; ks++) {
    const float* wp = Whh + (size_t)jcol * H_DIM + ks * 32 + quad * 8;
    float4 w0 = *(const float4*)wp;
    float4 w1 = *(const float4*)(wp + 4);
    halfx8 f;
    f[0] = (_Float16)w0.x; f[1] = (_Float16)w0.y;
    f[2] = (_Float16)w0.z; f[3] = (_Float16)w0.w;
    f[4] = (_Float16)w1.x; f[5] = (_Float16)w1.y;
    f[6] = (_Float16)w1.z; f[7] = (_Float16)w1.w;
    Bf[ks] = f;
  }
  const float bj  = bhh_p[jcol];
  const float aj  = alpha_of(jcol);
  const float oma = 1.0f - aj;

  // init h buffer 0 = 0
  for (int i = tid; i < 16 * 264; i += 1024) (&hB[0][0][0])[i] = (_Float16)0.0f;
  __syncthreads();

  // lane owns 4 (row, jcol) cells: rows quad*4+rg
  float  hreg[4], zc[4];
  size_t zoff[4];
#pragma unroll
  for (int rg = 0; rg < 4; rg++) {
    hreg[rg] = 0.0f;
    zoff[rg] = (size_t)(r0 + quad * 4 + rg) * H_DIM + jcol;
    zc[rg]   = zx_hall[zoff[rg]];  // t = 0
  }

  int p = 0;
  for (int t = 0; t < T_LEN; t++) {
    // z = h @ Whh^T : 8 MFMA in 2 independent chains
    f32x4 accE = {0.f, 0.f, 0.f, 0.f}, accO = {0.f, 0.f, 0.f, 0.f};
#pragma unroll
    for (int ks = 0; ks < 8; ks += 2) {
      halfx8 aE = *(const halfx8*)&hB[p][l15][ks * 32 + quad * 8];
      halfx8 aO = *(const halfx8*)&hB[p][l15][(ks + 1) * 32 + quad * 8];
      accE = __builtin_amdgcn_mfma_f32_16x16x32_f16(aE, Bf[ks],     accE, 0, 0, 0);
      accO = __builtin_amdgcn_mfma_f32_16x16x32_f16(aO, Bf[ks + 1], accO, 0, 0, 0);
    }

    // prefetch next zx (clamped; stale value unused)
    const size_t tb = (size_t)((t + 1 < T_LEN) ? t + 1 : t) * (B_SZ * H_DIM);
    float zn[4];
#pragma unroll
    for (int rg = 0; rg < 4; rg++) zn[rg] = zx_hall[tb + zoff[rg]];

    // epilogue: store pre-update h_t, fp32 blend, publish fp16 h
    const size_t tcur = (size_t)t * (B_SZ * H_DIM);
#pragma unroll
    for (int rg = 0; rg < 4; rg++) {
      const int r = quad * 4 + rg;
      float ho = hreg[rg];
      float hr = fast_tanh(zc[rg] + accE[rg] + accO[rg] + bj);
      float hn = oma * ho + aj * hr;
      zx_hall[tcur + zoff[rg]] = ho;        // h_all[t] = pre-update h
      hreg[rg] = hn;
      hB[p ^ 1][r][jcol] = (_Float16)hn;    // next step's A operand
    }

    lds_barrier();  // lgkm-only: global prefetch/stores stay in flight
    p ^= 1;
#pragma unroll
    for (int rg = 0; rg < 4; rg++) zc[rg] = zn[rg];
  }
}

// ---------------------------------------------------------------------------
extern "C" void kernel_launch(void* const* d_in, const int* in_sizes, int n_in,
                              void* d_out, int out_size, void* d_ws, size_t ws_size,
                              hipStream_t stream) {
  const float* x   = (const float*)d_in[0];
  const float* Wx0 = (const float*)d_in[1];
  const float* bx0 = (const float*)d_in[2];
  const float* Wx1 = (const float*)d_in[3];
  const float* bx1 = (const float*)d_in[4];
  const float* Wih = (const float*)d_in[5];
  const float* Whh = (const float*)d_in[6];
  const float* bih = (const float*)d_in[7];
  const float* bhh = (const float*)d_in[8];
  const float* Wh0 = (const float*)d_in[9];
  const float* bh0 = (const float*)d_in[10];
  const float* Wh1 = (const float*)d_in[11];
  const float* bh1 = (const float*)d_in[12];
  const float* Wg  = (const float*)d_in[13];
  const float* bg  = (const float*)d_in[14];
  float* out = (float*)d_out;

  float* buf = (float*)d_ws;  // 262144*256 floats = 256 MB
  const int MT = M_ROWS / 32; // 8192 m-tiles of 32 rows

  // 1) buf = tanh(x Wx0^T + bx0)        K=64
  gemm_f16<2, true><<<512, 512, 0, stream>>>(x, Wx0, bx0, buf, MT);
  // 2) buf = tanh(buf Wx1^T + bx1)      in-place
  gemm_f16<8, true><<<512, 512, 0, stream>>>(buf, Wx1, bx1, buf, MT);
  // 3) buf = buf Wih^T + bih (= zx)     in-place
  gemm_f16<8, false><<<512, 512, 0, stream>>>(buf, Wih, bih, buf, MT);
  // 4) serial recurrence (in place: zx -> h_all)
  rnn_serial<<<16, 1024, 0, stream>>>(buf, Whh, bhh);
  // 5) buf = tanh(buf Wh0^T + bh0)      in-place
  gemm_f16<8, true><<<512, 512, 0, stream>>>(buf, Wh0, bh0, buf, MT);
  // 6) buf = tanh(buf Wh1^T + bh1)      in-place
  gemm_f16<8, true><<<512, 512, 0, stream>>>(buf, Wh1, bh1, buf, MT);
  // 7) out = buf Wg^T + bg
  gemm_f16_out<<<512, 256, 0, stream>>>(buf, Wg, bg, out, MT);
}

// Round 5
// 1462.695 us; speedup vs baseline: 2.7330x; 1.1145x over previous
//
#include <hip/hip_runtime.h>
#include <cstddef>

// ---------------------------------------------------------------------------
// MT_RNN round 5: fp16 end-to-end intermediates + serial VALU diet.
// ws = two 128MB fp16 ping-pong halves (bufA/bufB), no aliasing:
//   1) bufA = tanh(x Wx0^T + bx0)            fp32 in  -> fp16 [M,256]
//   2) bufB = tanh(bufA Wx1^T + bx1)         fp16     -> fp16 [M,256]
//   3) bufA = bufB Wih^T + bih   TRANSPOSED  fp16     -> fp16 zxT [T,H,B]
//   4) serial: bufA (zxT) -> bufB (h_all fp16 [T,B,H]), 16 CUs
//   5) bufA = tanh(bufB Wh0^T + bh0)         fp16     -> fp16 [M,256]
//   6) bufB = tanh(bufA Wh1^T + bh1)         fp16     -> fp16 [M,256]
//   7) out  = bufB Wg^T + bg                 fp16     -> fp32 [M,64]
// ---------------------------------------------------------------------------

typedef _Float16 halfx8 __attribute__((ext_vector_type(8)));
typedef _Float16 halfx4 __attribute__((ext_vector_type(4)));
typedef float    f32x4  __attribute__((ext_vector_type(4)));

#define T_LEN 1024
#define B_SZ  256
#define H_DIM 256
#define M_ROWS (T_LEN * B_SZ)  // 262144

__device__ __forceinline__ float fast_tanh(float x) {
  float e = __expf(2.0f * x);
  return 1.0f - 2.0f / (e + 1.0f);
}

// sorted alpha assignment over 256 units: 86 x 0.001, 85 x 0.01, 85 x 0.1
__device__ __forceinline__ float alpha_of(int j) {
  return (j < 86) ? 0.001f : ((j < 171) ? 0.01f : 0.1f);
}

// barrier with LDS-only drain: global loads/stores stay in flight across it
__device__ __forceinline__ void lds_barrier() {
  asm volatile("s_waitcnt lgkmcnt(0)\n\ts_barrier" ::: "memory");
}

// ---------------------------------------------------------------------------
// fp16 MFMA GEMM, 8 waves, N=256, M-tile=32, grid-stride. W register-resident.
// INF32: A is fp32 (step 1 only), else fp16. ZXT: write transposed [T,H,B].
// MFMA 16x16x32 layouts (HW-verified rounds 2-4):
//   A: A[m=lane&15][k=8*(lane>>4)+i]   B: B[k=8*(lane>>4)+i][n=lane&15]
//   D: col n=lane&15, row m=4*(lane>>4)+reg
// ---------------------------------------------------------------------------
template <int KCH, bool TANH, bool INF32, bool ZXT>
__global__ __launch_bounds__(512, 2)
void gemm8(const void* __restrict__ Ap, const float* __restrict__ W,
           const float* __restrict__ bias, void* __restrict__ Cp, int mtiles) {
  constexpr int K  = KCH * 32;
  constexpr int KP = K + 8;
  __shared__ __attribute__((aligned(16))) _Float16 Ah[32][KP];

  const int tid  = threadIdx.x;
  const int lane = tid & 63;
  const int wave = tid >> 6;   // 0..7, owns 32 output columns
  const int l15  = lane & 15;
  const int quad = lane >> 4;
  const int jw   = wave * 32;

  // register-resident W fragments (fp16)
  halfx8 Bf[2][KCH];
  float  bcol[2];
  int    jj[2];
#pragma unroll
  for (int nt = 0; nt < 2; nt++) {
    jj[nt]   = jw + nt * 16 + l15;
    bcol[nt] = bias[jj[nt]];
#pragma unroll
    for (int ks = 0; ks < KCH; ks++) {
      const float* wp = W + (size_t)jj[nt] * K + ks * 32 + quad * 8;
      float4 w0 = *(const float4*)wp;
      float4 w1 = *(const float4*)(wp + 4);
      halfx8 f;
      f[0] = (_Float16)w0.x; f[1] = (_Float16)w0.y;
      f[2] = (_Float16)w0.z; f[3] = (_Float16)w0.w;
      f[4] = (_Float16)w1.x; f[5] = (_Float16)w1.y;
      f[6] = (_Float16)w1.z; f[7] = (_Float16)w1.w;
      Bf[nt][ks] = f;
    }
  }

  const int srow = tid >> 4;   // 0..31 (16 threads per row)
  const int sk4  = tid & 15;

  for (int bm = blockIdx.x; bm < mtiles; bm += gridDim.x) {
    // ---- stage A tile (32 x K) into LDS as fp16 ----
    if constexpr (INF32) {
      const float* A = (const float*)Ap + (size_t)bm * 32 * K;
      constexpr int SEG = K / 64;
      float4 tv[SEG];
#pragma unroll
      for (int s = 0; s < SEG; s++)
        tv[s] = *(const float4*)(A + (size_t)srow * K + (sk4 + s * 16) * 4);
#pragma unroll
      for (int s = 0; s < SEG; s++) {
        halfx4 h;
        h[0] = (_Float16)tv[s].x; h[1] = (_Float16)tv[s].y;
        h[2] = (_Float16)tv[s].z; h[3] = (_Float16)tv[s].w;
        *(halfx4*)&Ah[srow][(sk4 + s * 16) * 4] = h;
      }
    } else {
      const _Float16* A = (const _Float16*)Ap + (size_t)bm * 32 * K;
      constexpr int SEG = K / 128;  // halfx8 loads per thread
      halfx8 tv[SEG];
#pragma unroll
      for (int s = 0; s < SEG; s++)
        tv[s] = *(const halfx8*)(A + (size_t)srow * K + (sk4 + s * 16) * 8);
#pragma unroll
      for (int s = 0; s < SEG; s++)
        *(halfx8*)&Ah[srow][(sk4 + s * 16) * 8] = tv[s];
    }
    lds_barrier();

    f32x4 acc[2][2];
#pragma unroll
    for (int mi = 0; mi < 2; mi++)
#pragma unroll
      for (int nt = 0; nt < 2; nt++) acc[mi][nt] = (f32x4){0.f, 0.f, 0.f, 0.f};

#pragma unroll
    for (int ks = 0; ks < KCH; ks++)
#pragma unroll
      for (int mi = 0; mi < 2; mi++) {
        halfx8 a = *(const halfx8*)&Ah[mi * 16 + l15][ks * 32 + quad * 8];
#pragma unroll
        for (int nt = 0; nt < 2; nt++)
          acc[mi][nt] = __builtin_amdgcn_mfma_f32_16x16x32_f16(a, Bf[nt][ks], acc[mi][nt], 0, 0, 0);
      }

    // ---- epilogue ----
    if constexpr (ZXT) {
      // zxT[t][j][b]: t = bm>>3, b = (bm&7)*32 + mi*16 + quad*4 + rg
      _Float16* C = (_Float16*)Cp;
      const size_t tb = (size_t)(bm >> 3) * (H_DIM * B_SZ) + (bm & 7) * 32 + quad * 4;
#pragma unroll
      for (int mi = 0; mi < 2; mi++)
#pragma unroll
        for (int nt = 0; nt < 2; nt++) {
          halfx4 o;
#pragma unroll
          for (int rg = 0; rg < 4; rg++)
            o[rg] = (_Float16)(acc[mi][nt][rg] + bcol[nt]);
          *(halfx4*)(C + tb + (size_t)jj[nt] * B_SZ + mi * 16) = o;
        }
    } else {
      _Float16* C = (_Float16*)Cp;
#pragma unroll
      for (int mi = 0; mi < 2; mi++)
#pragma unroll
        for (int nt = 0; nt < 2; nt++)
#pragma unroll
          for (int rg = 0; rg < 4; rg++) {
            const int rowg = bm * 32 + mi * 16 + quad * 4 + rg;
            float v = acc[mi][nt][rg] + bcol[nt];
            if (TANH) v = fast_tanh(v);
            C[(size_t)rowg * 256 + jj[nt]] = (_Float16)v;
          }
    }
    lds_barrier();  // MFMA reads done before next tile's staging writes
  }
}

// ---------------------------------------------------------------------------
// Final projection: out[M,64] fp32 = A[M,256] fp16 @ Wg^T + bg. 4 waves.
// ---------------------------------------------------------------------------
__global__ __launch_bounds__(256, 2)
void gemm4_out(const _Float16* __restrict__ A, const float* __restrict__ W,
               const float* __restrict__ bias, float* __restrict__ C,
               int mtiles) {
  constexpr int K = 256, KCH = 8, KP = 264;
  __shared__ __attribute__((aligned(16))) _Float16 Ah[32][KP];

  const int tid  = threadIdx.x;
  const int lane = tid & 63;
  const int wave = tid >> 6;   // 0..3
  const int l15  = lane & 15;
  const int quad = lane >> 4;
  const int jcol = wave * 16 + l15;

  halfx8 Bf[KCH];
  const float bc = bias[jcol];
#pragma unroll
  for (int ks = 0; ks < KCH; ks++) {
    const float* wp = W + (size_t)jcol * K + ks * 32 + quad * 8;
    float4 w0 = *(const float4*)wp;
    float4 w1 = *(const float4*)(wp + 4);
    halfx8 f;
    f[0] = (_Float16)w0.x; f[1] = (_Float16)w0.y;
    f[2] = (_Float16)w0.z; f[3] = (_Float16)w0.w;
    f[4] = (_Float16)w1.x; f[5] = (_Float16)w1.y;
    f[6] = (_Float16)w1.z; f[7] = (_Float16)w1.w;
    Bf[ks] = f;
  }

  const int srow = tid >> 3;  // 0..31, 8 thr/row
  const int sk   = tid & 7;

  for (int bm = blockIdx.x; bm < mtiles; bm += gridDim.x) {
    const _Float16* Ab = A + (size_t)bm * 32 * K;
    halfx8 tv[4];
#pragma unroll
    for (int s = 0; s < 4; s++)
      tv[s] = *(const halfx8*)(Ab + (size_t)srow * K + (sk + s * 8) * 8);
#pragma unroll
    for (int s = 0; s < 4; s++)
      *(halfx8*)&Ah[srow][(sk + s * 8) * 8] = tv[s];
    lds_barrier();

    f32x4 acc[2];
#pragma unroll
    for (int mi = 0; mi < 2; mi++) acc[mi] = (f32x4){0.f, 0.f, 0.f, 0.f};
#pragma unroll
    for (int ks = 0; ks < KCH; ks++)
#pragma unroll
      for (int mi = 0; mi < 2; mi++) {
        halfx8 a = *(const halfx8*)&Ah[mi * 16 + l15][ks * 32 + quad * 8];
        acc[mi] = __builtin_amdgcn_mfma_f32_16x16x32_f16(a, Bf[ks], acc[mi], 0, 0, 0);
      }

#pragma unroll
    for (int mi = 0; mi < 2; mi++)
#pragma unroll
      for (int rg = 0; rg < 4; rg++) {
        const int rowg = bm * 32 + mi * 16 + quad * 4 + rg;
        C[(size_t)rowg * 64 + jcol] = acc[mi][rg] + bc;
      }
    lds_barrier();
  }
}

// ---------------------------------------------------------------------------
// Serial recurrence, VALU-dieted. 16 blocks x 1024 threads (16 waves,
// 4/SIMD). Block owns 16 batch rows; wave owns 16 h-columns.
// zxT fp16 [T,H,B]: ONE halfx4 (8B) load per lane per step off an
// incremented pointer (pipelined 2 steps ahead; tail overruns 256KB into
// the other ws half — in-bounds, discarded). h_all fp16 [T,B,H]: 4 x 2B
// stores off one pointer + immediate offsets. LDS double-buffer addresses
// precomputed; t-loop unrolled x2 so the buffer index is static. Single
// 8-deep MFMA chain. One lgkm-only barrier per step.
// ---------------------------------------------------------------------------
__global__ __launch_bounds__(1024, 4)
void rnn_serial(const _Float16* __restrict__ zxT,  // [T,H,B]
                _Float16* __restrict__ h_all,      // [T,B,H]
                const float* __restrict__ Whh,     // [H,H]
                const float* __restrict__ bhh_p)   // [H]
{
  __shared__ __attribute__((aligned(16))) _Float16 hB[2][16][264];

  const int tid  = threadIdx.x;
  const int lane = tid & 63;
  const int wave = tid >> 6;   // 0..15, owns 16 columns
  const int l15  = lane & 15;
  const int quad = lane >> 4;
  const int r0   = blockIdx.x * 16;
  const int jcol = wave * 16 + l15;

  // Whh B-fragments (fp16)
  halfx8 Bf[8];
#pragma unroll
  for (int ks = 0; ks < 8; ks++) {
    const float* wp = Whh + (size_t)jcol * H_DIM + ks * 32 + quad * 8;
    float4 w0 = *(const float4*)wp;
    float4 w1 = *(const float4*)(wp + 4);
    halfx8 f;
    f[0] = (_Float16)w0.x; f[1] = (_Float16)w0.y;
    f[2] = (_Float16)w0.z; f[3] = (_Float16)w0.w;
    f[4] = (_Float16)w1.x; f[5] = (_Float16)w1.y;
    f[6] = (_Float16)w1.z; f[7] = (_Float16)w1.w;
    Bf[ks] = f;
  }
  const float bj  = bhh_p[jcol];
  const float aj  = alpha_of(jcol);
  const float oma = 1.0f - aj;

  // init h buffer 0 = 0
  for (int i = tid; i < 16 * 264; i += 1024) (&hB[0][0][0])[i] = (_Float16)0.0f;
  __syncthreads();

  // precomputed LDS pointers (double-buffered)
  const _Float16* rdp[2] = {&hB[0][l15][quad * 8], &hB[1][l15][quad * 8]};
  _Float16*       wrp[2] = {&hB[1][quad * 4][jcol], &hB[0][quad * 4][jcol]};

  // global pointers
  const _Float16* zp = zxT + (size_t)jcol * B_SZ + r0 + quad * 4;  // [t][jcol][b4]
  _Float16*       hp = h_all + (size_t)(r0 + quad * 4) * H_DIM + jcol;
  constexpr int STRIDE = B_SZ * H_DIM;  // 65536 elements per t

  // zx pipeline: zc = fp32 zx[t] for current step; zA = raw zx[t+1]
  float  zc[4];
  halfx4 zA;
  {
    halfx4 z0 = *(const halfx4*)zp;
    zA = *(const halfx4*)(zp + STRIDE);
    zp += 2 * (size_t)STRIDE;
#pragma unroll
    for (int rg = 0; rg < 4; rg++) zc[rg] = (float)z0[rg];
  }

  // h state: fp32 + its published fp16 image
  float    hreg[4] = {0.f, 0.f, 0.f, 0.f};
  _Float16 hh[4]   = {(_Float16)0.f, (_Float16)0.f, (_Float16)0.f, (_Float16)0.f};

  auto step = [&](int p) {
    // prefetch zx two steps ahead
    halfx4 znew = *(const halfx4*)zp;
    zp += STRIDE;

    // z = h @ Whh^T (single 8-deep MFMA chain; 4 waves/SIMD hide latency)
    f32x4 acc = {0.f, 0.f, 0.f, 0.f};
    const _Float16* rd = rdp[p];
#pragma unroll
    for (int ks = 0; ks < 8; ks++) {
      halfx8 a = *(const halfx8*)(rd + ks * 32);
      acc = __builtin_amdgcn_mfma_f32_16x16x32_f16(a, Bf[ks], acc, 0, 0, 0);
    }

    // epilogue: store fp16 h_t (pre-update), blend fp32, publish fp16
    _Float16* wr = wrp[p];
#pragma unroll
    for (int rg = 0; rg < 4; rg++) {
      float ho = hreg[rg];
      float hr = fast_tanh(zc[rg] + acc[rg] + bj);
      float hn = oma * ho + aj * hr;
      hp[rg * H_DIM] = hh[rg];          // h_all[t] (offsets 0/512/1024/1536 B)
      hreg[rg] = hn;
      _Float16 hf = (_Float16)hn;
      hh[rg] = hf;
      wr[rg * 264] = hf;                // next step's A operand
    }
    hp += STRIDE;

    lds_barrier();  // lgkm-only: global loads/stores stay in flight

    // shift zx pipeline
#pragma unroll
    for (int rg = 0; rg < 4; rg++) zc[rg] = (float)zA[rg];
    zA = znew;
  };

  for (int it = 0; it < T_LEN / 2; ++it) {
    step(0);
    step(1);
  }
}

// ---------------------------------------------------------------------------
extern "C" void kernel_launch(void* const* d_in, const int* in_sizes, int n_in,
                              void* d_out, int out_size, void* d_ws, size_t ws_size,
                              hipStream_t stream) {
  const float* x   = (const float*)d_in[0];
  const float* Wx0 = (const float*)d_in[1];
  const float* bx0 = (const float*)d_in[2];
  const float* Wx1 = (const float*)d_in[3];
  const float* bx1 = (const float*)d_in[4];
  const float* Wih = (const float*)d_in[5];
  const float* Whh = (const float*)d_in[6];
  const float* bih = (const float*)d_in[7];
  const float* bhh = (const float*)d_in[8];
  const float* Wh0 = (const float*)d_in[9];
  const float* bh0 = (const float*)d_in[10];
  const float* Wh1 = (const float*)d_in[11];
  const float* bh1 = (const float*)d_in[12];
  const float* Wg  = (const float*)d_in[13];
  const float* bg  = (const float*)d_in[14];
  float* out = (float*)d_out;

  // two fp16 ping-pong halves, 128 MB each (ws >= 256 MB)
  _Float16* bufA = (_Float16*)d_ws;
  _Float16* bufB = bufA + (size_t)M_ROWS * 256;

  const int MT = M_ROWS / 32;  // 8192 m-tiles

  // 1) bufA = tanh(x Wx0^T + bx0)            fp32 -> fp16
  gemm8<2, true, true, false><<<512, 512, 0, stream>>>(x, Wx0, bx0, bufA, MT);
  // 2) bufB = tanh(bufA Wx1^T + bx1)
  gemm8<8, true, false, false><<<512, 512, 0, stream>>>(bufA, Wx1, bx1, bufB, MT);
  // 3) bufA = bufB Wih^T + bih, transposed zxT [T,H,B]
  gemm8<8, false, false, true><<<512, 512, 0, stream>>>(bufB, Wih, bih, bufA, MT);
  // 4) serial recurrence: zxT (bufA) -> h_all (bufB)
  rnn_serial<<<16, 1024, 0, stream>>>(bufA, bufB, Whh, bhh);
  // 5) bufA = tanh(bufB Wh0^T + bh0)
  gemm8<8, true, false, false><<<512, 512, 0, stream>>>(bufB, Wh0, bh0, bufA, MT);
  // 6) bufB = tanh(bufA Wh1^T + bh1)
  gemm8<8, true, false, false><<<512, 512, 0, stream>>>(bufA, Wh1, bh1, bufB, MT);
  // 7) out = bufB Wg^T + bg                  fp16 -> fp32
  gemm4_out<<<512, 256, 0, stream>>>(bufB, Wg, bg, out, MT);
}